// Round 20
// baseline (548.469 us; speedup 1.0000x reference)
//
#include <hip/hip_runtime.h>
#include <hip/hip_bf16.h>
#include <stdint.h>

#define NTOK 4096   // B*T = 2*2048
#define CD   1024
#define HD   4096
#define NE   8

typedef __attribute__((ext_vector_type(8))) short bf16x8;
typedef __attribute__((ext_vector_type(4))) float f32x4;
typedef __attribute__((ext_vector_type(4))) unsigned short us4;

#define BARR() asm volatile("s_barrier" ::: "memory")
#define LGKM0() asm volatile("s_waitcnt lgkmcnt(0)" ::: "memory")
#define VM2() asm volatile("s_waitcnt vmcnt(2)" ::: "memory")
#define VM1() asm volatile("s_waitcnt vmcnt(1)" ::: "memory")
#define VM0() asm volatile("s_waitcnt vmcnt(0)" ::: "memory")

__device__ __forceinline__ unsigned short f2bf(float f){
  __hip_bfloat16 h = __float2bfloat16(f);
  return *reinterpret_cast<unsigned short*>(&h);
}

// ---------------- router: logits (fp64 accum), softmax, top-2, renorm; x -> bf16 ----------------
__global__ __launch_bounds__(256) void router_kernel(
    const float* __restrict__ x, const float* __restrict__ rw,
    unsigned short* __restrict__ x_bf, int* __restrict__ top_i,
    float* __restrict__ top_w, int* __restrict__ counts){
  __shared__ float rw_lds[NE*CD];
  int tid = threadIdx.x;
  for (int i = tid; i < NE*CD/4; i += 256)
    ((float4*)rw_lds)[i] = ((const float4*)rw)[i];
  __syncthreads();
  int l = tid & 63, w = tid >> 6;
  int n = blockIdx.x*4 + w;

  float4 xv[4];
  #pragma unroll
  for (int j = 0; j < 4; ++j)
    xv[j] = ((const float4*)(x + (size_t)n*CD))[l + j*64];

  #pragma unroll
  for (int j = 0; j < 4; ++j){
    us4 o; o.x = f2bf(xv[j].x); o.y = f2bf(xv[j].y); o.z = f2bf(xv[j].z); o.w = f2bf(xv[j].w);
    *(us4*)(x_bf + (size_t)n*CD + l*4 + j*256) = o;
  }

  double le[NE];
  #pragma unroll
  for (int e = 0; e < NE; ++e){
    double p = 0.0;
    #pragma unroll
    for (int j = 0; j < 4; ++j){
      float4 rv = ((const float4*)(rw_lds + e*CD))[l + j*64];
      p += (double)xv[j].x*rv.x + (double)xv[j].y*rv.y + (double)xv[j].z*rv.z + (double)xv[j].w*rv.w;
    }
    #pragma unroll
    for (int d = 32; d >= 1; d >>= 1) p += __shfl_xor(p, d);
    le[e] = p;
  }
  if (l == 0){
    double m = le[0];
    #pragma unroll
    for (int e = 1; e < NE; ++e) m = le[e] > m ? le[e] : m;
    double pe[NE];
    #pragma unroll
    for (int e = 0; e < NE; ++e) pe[e] = exp(le[e]-m);
    int i0 = 0;
    #pragma unroll
    for (int e = 1; e < NE; ++e) if (pe[e] > pe[i0]) i0 = e;     // strict > : ties -> lower idx (matches lax.top_k)
    int i1 = (i0 == 0) ? 1 : 0;
    #pragma unroll
    for (int e = 0; e < NE; ++e){ if (e == i0) continue; if (pe[e] > pe[i1]) i1 = e; }
    double w0 = pe[i0], w1v = pe[i1], wsum = w0 + w1v;
    top_i[2*n] = i0; top_i[2*n+1] = i1;
    top_w[2*n] = (float)(w0/wsum); top_w[2*n+1] = (float)(w1v/wsum);
    atomicAdd(&counts[i0], 1); atomicAdd(&counts[i1], 1);
  }
}

// ---------------- tiny scan: 8-entry exclusive prefix ----------------
__global__ void scan_kernel(const int* __restrict__ counts, int* __restrict__ offsets, int* __restrict__ cursor){
  if (threadIdx.x == 0){
    int s = 0;
    for (int e = 0; e < NE; ++e){ offsets[e] = s; cursor[e] = s; s += counts[e]; }
  }
}

// ---------------- scatter tokens into expert-grouped lists ----------------
__global__ __launch_bounds__(256) void scatter_kernel(
    const int* __restrict__ top_i, const float* __restrict__ top_w,
    int* __restrict__ cursor, int* __restrict__ g_tok, float* __restrict__ g_w){
  int n = blockIdx.x*256 + threadIdx.x;
  #pragma unroll
  for (int k = 0; k < 2; ++k){
    int e = top_i[2*n+k];
    int pos = atomicAdd(&cursor[e], 1);
    g_tok[pos] = n;
    g_w[pos] = top_w[2*n+k];
  }
}

// ---------------- grouped GEMM, RING-3, NO-TRANSPOSE B (fp32 k-major direct) ----------------
// r16 engine (128x128 tile, BK=32, 8 waves of 64x32, 3-buf ring, expert-per-XCD, 24 waves/CU).
// NEW: B consumed directly from fp32 [E][KTOT][NDIM] (w1/w2 native layout) via reg-staging:
//   thread t: kp=t>>5 (k-pair 2kp,2kp+1), n4=t&31 (rows n4*4..+3);
//   LOADB(t): 2x float4 at rows (2kp, 2kp+1), cols n0+n4*4 (coalesced 512B/wave);
//   WRITEB: 4x pack(bf16(lo),bf16(hi)) -> ds_write_b32 at row*64 + 16*((kp>>2)^X(row)) + (kp&3)*4
//   -> EXACT same LDS layout contract as the old transposed staging (reads untouched).
// Pipeline (3 VMEM/iter: B first, A second; derived waits):
//   iter kt: LGKM0+BARR; LOADB(kt+1); STAGE_A(kt+2); ds_read+MFMA(kt);
//            VM1 (forces A(kt+1)+B(kt+1), keeps A(kt+2)); WRITEB -> buf(kt+1).
// Eliminates both transpose kernels (426MB traffic + serial time). EPI as before.
template<int KLEN, int SPLITK, int EPI>
__global__ __launch_bounds__(512, 6) void gemm_ring3(
    const unsigned short* __restrict__ A_src,
    const float* __restrict__ B_src,
    unsigned short* __restrict__ h_out,
    float* __restrict__ outp,
    const int* __restrict__ g_tok,
    const float* __restrict__ g_w,
    const int* __restrict__ counts,
    const int* __restrict__ offsets,
    int NDIM, int KTOT){
  constexpr int NT = KLEN/32;
  constexpr int ZPX = (NE*SPLITK)/8;           // z-slabs per XCD
  __shared__ alignas(128) char lds[49152];     // 3 bufs x 16KB: A [0,8K) B [8K,16K)

  // ---- expert-per-XCD decode (r15/r16 verified: FETCH 315->59MB) ----
  int GN = gridDim.x, GY = gridDim.y;
  int p  = blockIdx.x + GN*(blockIdx.y + GY*blockIdx.z);
  int k8 = p & 7;
  int i  = p >> 3;
  int s  = i / (GN*GY);
  int r  = i - s*(GN*GY);
  int y  = r % GY;
  int xb = r / GY;
  int z  = k8*ZPX + s;

  int e  = (SPLITK == 1) ? z : (z / SPLITK);
  int kz = (SPLITK == 1) ? 0 : (z % SPLITK);
  int n_e = counts[e];
  int m0 = y*128;
  if (m0 >= n_e) return;
  int n0 = xb*128;
  int g_base = offsets[e];
  int kstart = kz*KLEN;

  int tid = threadIdx.x, l = tid & 63, w = tid >> 6;   // 8 waves
  int wr = w >> 2, wc = w & 3;                         // wave tile: rows wr*64, cols wc*32
  int lrow = l & 15, q = l >> 4;

  // ---- A staging: 1 global_load_lds per thread (8KB/tile), swizzled source ----
  const unsigned short* srcA;
  uint32_t dstA = (uint32_t)tid*16u;
  {
    int row = tid >> 2, c = tid & 3;
    int cs = c ^ (row & 3) ^ ((row >> 2) & 3);
    int rg = m0 + row; if (rg > n_e-1) rg = n_e-1;     // clamp partial tile
    size_t arow = (EPI == 0) ? (size_t)g_tok[g_base + rg] : (size_t)(g_base + rg);
    srcA = A_src + arow*(size_t)KTOT + kstart + cs*8;
  }
  auto STAGE_A = [&](int t, uint32_t bufoff){
    __builtin_amdgcn_global_load_lds(
      (const __attribute__((address_space(1))) void*)(srcA + (size_t)t*32),
      (__attribute__((address_space(3))) void*)&lds[dstA + bufoff], 16, 0, 0);
  };

  // ---- B reg-staging geometry ----
  int kp = tid >> 5, n4 = tid & 31;
  const float* bptr = B_src + ((size_t)e*KTOT + kstart + 2*kp)*NDIM + n0 + n4*4;
  uint32_t bw[4];
  #pragma unroll
  for (int j = 0; j < 4; ++j){
    int row = n4*4 + j;
    int Xr = (row & 3) ^ ((row >> 2) & 3);
    bw[j] = 8192u + (uint32_t)(row*64) + 16u*(uint32_t)((kp >> 2) ^ Xr) + (uint32_t)((kp & 3)*4);
  }
  float4 va, vb;
  auto LOADB = [&](int t){
    const float* pp = bptr + (size_t)t*32*NDIM;
    va = *(const float4*)pp;
    vb = *(const float4*)(pp + NDIM);
  };
  auto WRITEB = [&](uint32_t bufoff){
    uint32_t u0 = (uint32_t)f2bf(va.x) | ((uint32_t)f2bf(vb.x) << 16);
    uint32_t u1 = (uint32_t)f2bf(va.y) | ((uint32_t)f2bf(vb.y) << 16);
    uint32_t u2 = (uint32_t)f2bf(va.z) | ((uint32_t)f2bf(vb.z) << 16);
    uint32_t u3 = (uint32_t)f2bf(va.w) | ((uint32_t)f2bf(vb.w) << 16);
    *(uint32_t*)&lds[bw[0] + bufoff] = u0;
    *(uint32_t*)&lds[bw[1] + bufoff] = u1;
    *(uint32_t*)&lds[bw[2] + bufoff] = u2;
    *(uint32_t*)&lds[bw[3] + bufoff] = u3;
  };

  // ---- fragment read offsets (unchanged contract) ----
  uint32_t a_off[4], b_off[2];
  #pragma unroll
  for (int m = 0; m < 4; ++m){
    int ra = wr*64 + m*16 + lrow;
    int Xa = (ra & 3) ^ ((ra >> 2) & 3);
    a_off[m] = (uint32_t)(ra*64) + 16u*(uint32_t)(q ^ Xa);
  }
  #pragma unroll
  for (int n = 0; n < 2; ++n){
    int rb = wc*32 + n*16 + lrow;
    int Xb = (rb & 3) ^ ((rb >> 2) & 3);
    b_off[n] = 8192u + (uint32_t)(rb*64) + 16u*(uint32_t)(q ^ Xb);
  }

  f32x4 acc[4][2] = {};
  const uint32_t B0 = 0u, B1 = 16384u, B2 = 32768u;
  uint32_t bufo[3] = {B0, B1, B2};

  // prologue: B(0) regs + A(0),A(1) staged; land B(0), write buf0; land A(0)
  LOADB(0); STAGE_A(0, B0); STAGE_A(1, B1);
  VM2();            // forces B(0) (oldest 2 of 4), keeps A(0),A(1)
  WRITEB(B0);
  VM1();            // forces A(0), keeps A(1)

  #pragma unroll 1
  for (int kt = 0; kt < NT; ++kt){
    LGKM0();                                   // my ds_writes (and reads) drained
    BARR();                                    // tile kt fully visible; buf(kt+1)/(kt+2) free
    if (kt + 1 < NT) LOADB(kt + 1);
    if (kt + 2 < NT) STAGE_A(kt + 2, bufo[(kt+2)%3]);
    uint32_t ro = bufo[kt%3];
    bf16x8 av[4], bv[2];
    #pragma unroll
    for (int m = 0; m < 4; ++m)
      av[m] = *(const bf16x8*)&lds[a_off[m] + ro];
    #pragma unroll
    for (int n = 0; n < 2; ++n)
      bv[n] = *(const bf16x8*)&lds[b_off[n] + ro];
    __builtin_amdgcn_s_setprio(1);
    #pragma unroll
    for (int m = 0; m < 4; ++m)
      #pragma unroll
      for (int n = 0; n < 2; ++n)
        acc[m][n] = __builtin_amdgcn_mfma_f32_16x16x32_bf16(av[m], bv[n], acc[m][n], 0, 0, 0);
    __builtin_amdgcn_s_setprio(0);
    if (kt + 1 < NT){
      if (kt + 2 < NT) { VM1(); } else { VM0(); }   // B(kt+1)+A(kt+1) landed; keep A(kt+2)
      WRITEB(bufo[(kt+1)%3]);
    }
  }

  // C/D layout (verified m89): col = lane&15, row = (lane>>4)*4 + j
  if (EPI == 0){
    #pragma unroll
    for (int m = 0; m < 4; ++m){
      #pragma unroll
      for (int jj = 0; jj < 4; ++jj){
        int rr = m0 + wr*64 + m*16 + q*4 + jj;
        if (rr < n_e){
          unsigned short* hp = h_out + (size_t)(g_base + rr)*NDIM + n0 + wc*32 + lrow;
          #pragma unroll
          for (int n = 0; n < 2; ++n){
            float v = acc[m][n][jj];
            v = 0.5f*v*(1.0f + erff(v*0.70710678118654752f));   // exact GELU
            hp[n*16] = f2bf(v);
          }
        }
      }
    }
  } else {
    #pragma unroll
    for (int m = 0; m < 4; ++m){
      #pragma unroll
      for (int jj = 0; jj < 4; ++jj){
        int rr = m0 + wr*64 + m*16 + q*4 + jj;
        if (rr < n_e){
          int slot = g_base + rr;
          int tt = g_tok[slot];
          float wgt = g_w[slot];
          float* op = outp + (size_t)tt*NDIM + n0 + wc*32 + lrow;
          #pragma unroll
          for (int n = 0; n < 2; ++n)
            atomicAdd(op + n*16, wgt*acc[m][n][jj]);
        }
      }
    }
  }
}

extern "C" void kernel_launch(void* const* d_in, const int* in_sizes, int n_in,
                              void* d_out, int out_size, void* d_ws, size_t ws_size,
                              hipStream_t stream) {
  const float* x  = (const float*)d_in[0];
  const float* rw = (const float*)d_in[1];
  const float* w1 = (const float*)d_in[2];
  const float* w2 = (const float*)d_in[3];

  size_t off = 0;
  auto alloc = [&](size_t sz) -> char* {
    char* p = (char*)d_ws + off;
    off += (sz + 255) & ~(size_t)255;
    return p;
  };
  unsigned short* x_bf = (unsigned short*)alloc((size_t)NTOK*CD*2);   // 8.4 MB
  unsigned short* hbuf = (unsigned short*)alloc((size_t)NTOK*2*HD*2); // 67 MB  [slot][H]
  int*   top_i  = (int*)alloc(NTOK*2*4);
  float* top_w  = (float*)alloc(NTOK*2*4);
  int*   counts = (int*)alloc(64);
  int*   offs   = (int*)alloc(64);
  int*   cursor = (int*)alloc(64);
  int*   g_tok  = (int*)alloc(NTOK*2*4);
  float* g_w    = (float*)alloc(NTOK*2*4);
  (void)ws_size; (void)in_sizes; (void)n_in; (void)out_size;

  hipMemsetAsync(d_out, 0, (size_t)NTOK*CD*4, stream);
  hipMemsetAsync(counts, 0, 64, stream);

  router_kernel<<<dim3(NTOK/4), dim3(256), 0, stream>>>(x, rw, x_bf, top_i, top_w, counts);
  scan_kernel<<<dim3(1), dim3(64), 0, stream>>>(counts, offs, cursor);
  scatter_kernel<<<dim3(NTOK/256), dim3(256), 0, stream>>>(top_i, top_w, cursor, g_tok, g_w);

  // GEMM1: h = gelu(x @ w1^T-implicit)  B = w1 fp32 [E][CD][HD] k-major; grid 32x12x8
  gemm_ring3<CD, 1, 0><<<dim3(HD/128, 12, NE), dim3(512), 0, stream>>>(
      x_bf, w1, hbuf, (float*)nullptr, g_tok, g_w, counts, offs, HD, CD);
  // GEMM2: out[token] += w * (h @ w2^T-implicit)  B = w2 fp32 [E][HD][CD]; split-K x2; 8x12x16
  gemm_ring3<HD/2, 2, 1><<<dim3(CD/128, 12, NE*2), dim3(512), 0, stream>>>(
      hbuf, w2, (unsigned short*)nullptr, (float*)d_out, g_tok, g_w, counts, offs, CD, HD);
}